// Round 4
// baseline (672.976 us; speedup 1.0000x reference)
//
#include <hip/hip_runtime.h>

#define DEV __device__ __forceinline__

typedef unsigned short u16;
typedef unsigned int   u32;
typedef __attribute__((ext_vector_type(8))) short short8;   // 8 x bf16 (4 VGPRs)
typedef __attribute__((ext_vector_type(4))) float f32x4;

DEV u16 f2bf(float f) {                       // f32 -> bf16 RNE
  u32 u = __builtin_bit_cast(u32, f);
  u = (u + 0x7FFFu + ((u >> 16) & 1u)) >> 16;
  return (u16)u;
}

DEV void gl_lds16(const void* g, void* l) {   // async global->LDS, 16B/lane
  __builtin_amdgcn_global_load_lds((const __attribute__((address_space(1))) void*)g,
                                   (__attribute__((address_space(3))) void*)l, 16, 0, 0);
}

DEV f32x4 mfma_bf16(short8 a, short8 b, f32x4 c) {
  return __builtin_amdgcn_mfma_f32_16x16x32_bf16(a, b, c, 0, 0, 0);
}

#define BAR() do { asm volatile("" ::: "memory"); __builtin_amdgcn_s_barrier(); asm volatile("" ::: "memory"); } while (0)
#define WAITV(N) asm volatile("s_waitcnt vmcnt(" #N ")" ::: "memory")

// ---------------- f32 -> bf16 cast (vectorized) ----------------
__global__ __launch_bounds__(256) void f32_to_bf16_k(const float* __restrict__ in,
                                                     u16* __restrict__ out, int n4) {
  int stride = gridDim.x * 256;
  for (int i = blockIdx.x * 256 + threadIdx.x; i < n4; i += stride) {
    float4 v = ((const float4*)in)[i];
    u32 lo = (u32)f2bf(v.x) | ((u32)f2bf(v.y) << 16);
    u32 hi = (u32)f2bf(v.z) | ((u32)f2bf(v.w) << 16);
    ((uint2*)out)[i] = make_uint2(lo, hi);
  }
}

// ---------------- transpose + cast: W[K][N] f32 -> WT[Npad][K] bf16 ----------------
__global__ __launch_bounds__(256) void transpose_to_bf16_k(const float* __restrict__ W,
                                                           u16* __restrict__ WT,
                                                           int K, int N) {
  __shared__ u16 T[64][72];
  int k0 = blockIdx.x * 64, n0 = blockIdx.y * 64;
  int t = threadIdx.x;
#pragma unroll
  for (int i = 0; i < 4; ++i) {
    int c = t + i * 256;
    int kr = c >> 4, nc = (c & 15) * 4;
    float4 v = make_float4(0.f, 0.f, 0.f, 0.f);
    if (n0 + nc < N) v = *(const float4*)(W + (size_t)(k0 + kr) * N + n0 + nc);
    T[nc + 0][kr] = f2bf(v.x);
    T[nc + 1][kr] = f2bf(v.y);
    T[nc + 2][kr] = f2bf(v.z);
    T[nc + 3][kr] = f2bf(v.w);
  }
  __syncthreads();
#pragma unroll
  for (int i = 0; i < 2; ++i) {
    int c = t + i * 256;
    int nr = c >> 3, kc = (c & 7) * 8;
    int4 v = *(const int4*)&T[nr][kc];
    *(int4*)(WT + (size_t)(n0 + nr) * K + k0 + kc) = v;
  }
}

// ---------------- 256x256 8-phase bf16 GEMM (T1+T2+T3+T4+T5) ----------------
// A [M][K] bf16, BT [Npad][K] bf16. MODE 0: C f32 = A*BT^T + bias (cols<Nguard).
// MODE 1: fused QKV epilogue: YaRN rope + split into q/k/v bf16.
template<int MH>
DEV void rd_a(short8 (&af)[4][2], const u16* lb, int rowA, int sl0, int sl1) {
#pragma unroll
  for (int ii = 0; ii < 4; ++ii) {
    af[ii][0] = *(const short8*)(lb + rowA + (MH * 64 + ii * 16) * 64 + sl0);
    af[ii][1] = *(const short8*)(lb + rowA + (MH * 64 + ii * 16) * 64 + sl1);
  }
}
template<int JJ>
DEV void rd_b(short8 (&bf)[4][2], const u16* lb, int rowB, int sl0, int sl1) {
  bf[JJ][0] = *(const short8*)(lb + rowB + JJ * 16 * 64 + sl0);
  bf[JJ][1] = *(const short8*)(lb + rowB + JJ * 16 * 64 + sl1);
}
template<int MH, int J0, int J1>
DEV void phase_mfma(f32x4 (&acc)[8][4], short8 (&af)[4][2], short8 (&bf)[4][2]) {
  __builtin_amdgcn_s_setprio(1);
#pragma unroll
  for (int ii = 0; ii < 4; ++ii) {
    acc[MH * 4 + ii][J0] = mfma_bf16(af[ii][0], bf[J0][0], acc[MH * 4 + ii][J0]);
    acc[MH * 4 + ii][J0] = mfma_bf16(af[ii][1], bf[J0][1], acc[MH * 4 + ii][J0]);
    acc[MH * 4 + ii][J1] = mfma_bf16(af[ii][0], bf[J1][0], acc[MH * 4 + ii][J1]);
    acc[MH * 4 + ii][J1] = mfma_bf16(af[ii][1], bf[J1][1], acc[MH * 4 + ii][J1]);
  }
  __builtin_amdgcn_s_setprio(0);
}
DEV void stage_half(const u16* g0, size_t Ks, u16* l0) {  // one 128-row half-tile
  gl_lds16(g0, l0);
  gl_lds16(g0 + 64 * Ks, l0 + 4096);
}

template<int MODE>
__global__ __launch_bounds__(512, 2) void gemm8p_k(
    const u16* __restrict__ A, const u16* __restrict__ BT,
    float* __restrict__ C, const float* __restrict__ bias,
    int K, int Ntiles, int ldc, int Nguard,
    const int* __restrict__ posids,
    u16* __restrict__ qout, u16* __restrict__ kout, u16* __restrict__ vout) {
  __shared__ u16 lds[65536];                  // 128 KiB: [buf][A 16K | B 16K] u16
  const int NT = K >> 6;
  int nwg = gridDim.x;
  int bid = blockIdx.x;
  int swz = (bid & 7) * (nwg >> 3) + (bid >> 3);   // XCD swizzle (nwg % 8 == 0)
  int m0 = (swz / Ntiles) * 256, n0 = (swz % Ntiles) * 256;

  int t = threadIdx.x, w = t >> 6, l = t & 63;
  int lr = l & 15, lg = l >> 4;
  int wm = w >> 2, wn = w & 3;
  // staging source (swizzled slot so linear LDS + XOR read = identity)
  int rl = t >> 3;                            // row 0..63 within a 64-row chunk
  int ss = (t & 7) ^ (rl & 7);
  const u16* Asrc = A + (size_t)(m0 + rl) * K + ss * 8;
  const u16* Bsrc = BT + (size_t)(n0 + rl) * K + ss * 8;
  int wofs = w * 512;                         // wave-uniform LDS chunk offset
  // ds_read addressing (XOR-swizzled slot)
  int rowA = (wm * 128 + lr) * 64;
  int rowB = (wn * 64 + lr) * 64;
  int sl0 = ((lg) ^ (lr & 7)) * 8;
  int sl1 = ((4 + lg) ^ (lr & 7)) * 8;

  f32x4 acc[8][4];
#pragma unroll
  for (int i = 0; i < 8; ++i)
#pragma unroll
    for (int j = 0; j < 4; ++j) acc[i][j] = (f32x4){0.f, 0.f, 0.f, 0.f};

  // prologue: tile0 all 4 halves (B0,B1,A0,A1), tile1 {B0,B1,A0}; vmcnt(6)
  stage_half(Bsrc,            K, lds + 16384 + wofs);
  stage_half(Bsrc + 128 * K,  K, lds + 16384 + 8192 + wofs);
  stage_half(Asrc,            K, lds + wofs);
  stage_half(Asrc + 128 * K,  K, lds + 8192 + wofs);
  if (NT > 1) {
    stage_half(Bsrc + 64,           K, lds + 32768 + 16384 + wofs);
    stage_half(Bsrc + 128 * K + 64, K, lds + 32768 + 16384 + 8192 + wofs);
    stage_half(Asrc + 64,           K, lds + 32768 + wofs);
  }
  WAITV(6);
  BAR();

  int p = 0;
  short8 af[4][2], bf[4][2];
  for (int kt = 0; kt < NT; ++kt) {
    const u16* lb = lds + p * 32768;
    u16* lo = lds + (p ^ 1) * 32768;
    u16* lc = lds + p * 32768;
    size_t kc1 = (size_t)(kt + 1) * 64, kc2 = (size_t)(kt + 2) * 64;
    // P0: read A-low + B0,B1 ; stage A-half1(kt+1) -> buf p^1
    rd_a<0>(af, lb, rowA, sl0, sl1);
    rd_b<0>(bf, lb + 16384, rowB, sl0, sl1);
    rd_b<1>(bf, lb + 16384, rowB, sl0, sl1);
    if (kt + 1 < NT) stage_half(Asrc + 128 * K + kc1, K, lo + 8192 + wofs);
    BAR();
    phase_mfma<0, 0, 1>(acc, af, bf);
    BAR();
    // P1: read B2,B3
    rd_b<2>(bf, lb + 16384, rowB, sl0, sl1);
    rd_b<3>(bf, lb + 16384, rowB, sl0, sl1);
    BAR();
    phase_mfma<0, 2, 3>(acc, af, bf);
    BAR();
    // P2: read A-high ; stage B-half0(kt+2) -> buf p (B reads done at P1)
    rd_a<1>(af, lb, rowA, sl0, sl1);
    if (kt + 2 < NT) stage_half(Bsrc + kc2, K, lc + 16384 + wofs);
    BAR();
    phase_mfma<1, 2, 3>(acc, af, bf);
    BAR();
    // P3: stage B-half1(kt+2), A-half0(kt+2) -> buf p (A reads done at P2)
    if (kt + 2 < NT) {
      stage_half(Bsrc + 128 * K + kc2, K, lc + 16384 + 8192 + wofs);
      stage_half(Asrc + kc2,           K, lc + wofs);
    }
    BAR();
    phase_mfma<1, 0, 1>(acc, af, bf);
    if (kt < NT - 1) {
      if (kt + 2 < NT) { WAITV(6); } else { WAITV(0); }
    }
    BAR();
    p ^= 1;
  }

  // -------- epilogue --------
  if constexpr (MODE == 0) {
#pragma unroll
    for (int jj = 0; jj < 4; ++jj) {
      int col = n0 + wn * 64 + jj * 16 + lr;
      if (col < Nguard) {
        float bv = bias[col];
#pragma unroll
        for (int ii = 0; ii < 8; ++ii) {
          int row = m0 + wm * 128 + ii * 16 + lg * 4;
#pragma unroll
          for (int r = 0; r < 4; ++r)
            C[(size_t)(row + r) * ldc + col] = acc[ii][jj][r] + bv;
        }
      }
    }
  } else {
    int colbase = n0 + wn * 64;               // multiple of 64 (one head per wave)
    bool isQ = colbase < 4096;
    bool isV = colbase >= 4608;
    if (isV) {
#pragma unroll
      for (int jj = 0; jj < 4; ++jj) {
        int col = colbase + jj * 16 + lr;
        float bv = bias[col];
#pragma unroll
        for (int ii = 0; ii < 8; ++ii) {
          int row = m0 + wm * 128 + ii * 16 + lg * 4;
#pragma unroll
          for (int r = 0; r < 4; ++r)
            vout[(size_t)(row + r) * 512 + (col - 4608)] = f2bf(acc[ii][jj][r] + bv);
        }
      }
    } else {
      // YaRN rope: pairs (jj, jj+2) = head cols (hc, hc+32), same lane
      float invf[2];
#pragma unroll
      for (int pp = 0; pp < 2; ++pp) {
        int f = pp * 16 + lr;
        const double PI = 3.14159265358979323846;
        double pf = exp(log(150000.0) * ((double)f / 32.0));
        double extrap = 1.0 / pf;
        double interp = extrap / 32.0;
        double l2b = 2.0 * log(150000.0);
        double low  = floor(64.0 * log(4096.0 / (32.0 * 2.0 * PI)) / l2b);
        double high = ceil (64.0 * log(4096.0 / ( 1.0 * 2.0 * PI)) / l2b);
        if (low < 0.0) low = 0.0;
        if (high > 63.0) high = 63.0;
        double ramp = ((double)f - low) / fmax(high - low, 0.001);
        ramp = fmin(fmax(ramp, 0.0), 1.0);
        invf[pp] = (float)(interp * ramp + extrap * (1.0 - ramp));
      }
      float mscale = (float)(0.1 * log(32.0) + 1.0);
      float qsc = isQ ? 0.125f : 1.0f;
#pragma unroll
      for (int jj = 0; jj < 2; ++jj) {
        int col_lo = colbase + jj * 16 + lr;
        int col_hi = col_lo + 32;
        float blo = bias[col_lo], bhi = bias[col_hi];
#pragma unroll
        for (int ii = 0; ii < 8; ++ii) {
          int row = m0 + wm * 128 + ii * 16 + lg * 4;
#pragma unroll
          for (int r = 0; r < 4; ++r) {
            int ps = posids[row + r];
            float fr = (float)ps * invf[jj];
            float c = cosf(fr) * mscale, s = sinf(fr) * mscale;
            float x1 = acc[ii][jj][r] + blo;
            float x2 = acc[ii][jj + 2][r] + bhi;
            float o1 = (x1 * c - x2 * s) * qsc;
            float o2 = (x2 * c + x1 * s) * qsc;
            if (isQ) {
              qout[(size_t)(row + r) * 4096 + col_lo] = f2bf(o1);
              qout[(size_t)(row + r) * 4096 + col_hi] = f2bf(o2);
            } else {
              kout[(size_t)(row + r) * 512 + (col_lo - 4096)] = f2bf(o1);
              kout[(size_t)(row + r) * 512 + (col_hi - 4096)] = f2bf(o2);
            }
          }
        }
      }
    }
  }
}

// ---------------- banded attention with sinks ----------------
__global__ __launch_bounds__(256, 1) void attn_k(const u16* __restrict__ qb,
                                                 const u16* __restrict__ kb,
                                                 const u16* __restrict__ vb,
                                                 const float* __restrict__ sinks,
                                                 u16* __restrict__ attnb) {
  int n = blockIdx.x, h = blockIdx.y;
  int kvh = h >> 3;
  int t = threadIdx.x, w = t >> 6, l = t & 63;
  int lr = l & 15, lg = l >> 4;
  __shared__ u16 Ks[256 * 72];
  __shared__ u16 VT[64 * 264];
  __shared__ u16 Ps[4][32 * 136];
  float sink = sinks[h];

  for (int c = t; c < 2048; c += 256) {
    int m = c >> 3, j = c & 7;
    int s = n * 128 - 128 + m;
    int4 kvl = make_int4(0, 0, 0, 0), vvl = make_int4(0, 0, 0, 0);
    if (s >= 0) {
      kvl = *(const int4*)(kb + (size_t)s * 512 + kvh * 64 + j * 8);
      vvl = *(const int4*)(vb + (size_t)s * 512 + kvh * 64 + j * 8);
    }
    *(int4*)(Ks + m * 72 + j * 8) = kvl;
    const u16* ve = (const u16*)&vvl;
#pragma unroll
    for (int e = 0; e < 8; ++e) VT[(j * 8 + e) * 264 + m] = ve[e];
  }
  __syncthreads();

  short8 aq[2][2];
#pragma unroll
  for (int i = 0; i < 2; ++i)
#pragma unroll
    for (int kk = 0; kk < 2; ++kk)
      aq[i][kk] = *(const short8*)(qb + (size_t)(n * 128 + w * 32 + i * 16 + lr) * 4096
                                      + h * 64 + kk * 32 + lg * 8);

  f32x4 p[2][16];
#pragma unroll
  for (int ct = 0; ct < 16; ++ct) {
    short8 b0 = *(const short8*)(Ks + (ct * 16 + lr) * 72 + lg * 8);
    short8 b1 = *(const short8*)(Ks + (ct * 16 + lr) * 72 + 32 + lg * 8);
#pragma unroll
    for (int i = 0; i < 2; ++i) {
      f32x4 z = (f32x4){0.f, 0.f, 0.f, 0.f};
      z = mfma_bf16(aq[i][0], b0, z);
      z = mfma_bf16(aq[i][1], b1, z);
      p[i][ct] = z;
    }
  }

  float invden[2][4];
#pragma unroll
  for (int i = 0; i < 2; ++i) {
#pragma unroll
    for (int r = 0; r < 4; ++r) {
      int q = w * 32 + i * 16 + lg * 4 + r;
      float best = -1e30f;
#pragma unroll
      for (int ct = 0; ct < 16; ++ct) {
        int m = ct * 16 + lr;
        int delta = q + 128 - m;
        bool valid = (delta >= 0) & (delta < 128) & ((n > 0) | (m >= 128));
        float v = valid ? p[i][ct][r] : -1e30f;
        p[i][ct][r] = v;
        best = fmaxf(best, v);
      }
#pragma unroll
      for (int d = 1; d < 16; d <<= 1) best = fmaxf(best, __shfl_xor(best, d, 64));
      best = fmaxf(best, sink);
      float sum = 0.f;
#pragma unroll
      for (int ct = 0; ct < 16; ++ct) {
        float e = expf(p[i][ct][r] - best);
        p[i][ct][r] = e;
        sum += e;
      }
#pragma unroll
      for (int d = 1; d < 16; d <<= 1) sum += __shfl_xor(sum, d, 64);
      sum += expf(sink - best);
      invden[i][r] = 1.0f / sum;
    }
  }

  f32x4 o[2][4];
#pragma unroll
  for (int qt = 0; qt < 2; ++qt)
#pragma unroll
    for (int dt = 0; dt < 4; ++dt) o[qt][dt] = (f32x4){0.f, 0.f, 0.f, 0.f};

  u16* Pw = Ps[w];
#pragma unroll
  for (int half = 0; half < 2; ++half) {
#pragma unroll
    for (int i = 0; i < 2; ++i)
#pragma unroll
      for (int ct = 0; ct < 8; ++ct)
#pragma unroll
        for (int r = 0; r < 4; ++r)
          Pw[(i * 16 + lg * 4 + r) * 136 + ct * 16 + lr] = f2bf(p[i][half * 8 + ct][r]);
#pragma unroll
    for (int ks = 0; ks < 4; ++ks) {
      short8 bv[4];
#pragma unroll
      for (int dt = 0; dt < 4; ++dt)
        bv[dt] = *(const short8*)(VT + (dt * 16 + lr) * 264 + half * 128 + ks * 32 + lg * 8);
#pragma unroll
      for (int qt = 0; qt < 2; ++qt) {
        short8 av = *(const short8*)(Pw + (qt * 16 + lr) * 136 + ks * 32 + lg * 8);
#pragma unroll
        for (int dt = 0; dt < 4; ++dt)
          o[qt][dt] = mfma_bf16(av, bv[dt], o[qt][dt]);
      }
    }
  }

#pragma unroll
  for (int qt = 0; qt < 2; ++qt)
#pragma unroll
    for (int dt = 0; dt < 4; ++dt)
#pragma unroll
      for (int r = 0; r < 4; ++r) {
        int row = n * 128 + w * 32 + qt * 16 + lg * 4 + r;
        int col = h * 64 + dt * 16 + lr;
        attnb[(size_t)row * 4096 + col] = f2bf(o[qt][dt][r] * invden[qt][r]);
      }
}

// ---------------- launch ----------------
extern "C" void kernel_launch(void* const* d_in, const int* in_sizes, int n_in,
                              void* d_out, int out_size, void* d_ws, size_t ws_size,
                              hipStream_t stream) {
  const float* hidden = (const float*)d_in[0];
  const int*   pos    = (const int*)d_in[1];
  const float* w_qkv  = (const float*)d_in[2];
  const float* b_qkv  = (const float*)d_in[3];
  const float* w_o    = (const float*)d_in[4];
  const float* b_o    = (const float*)d_in[5];
  const float* sinks  = (const float*)d_in[6];
  float* out = (float*)d_out;
  char* ws = (char*)d_ws;

  // workspace layout (bytes, 256-aligned), total ~130 MB
  u16* hbf   = (u16*)(ws + 0);               // [4096][2880] bf16
  u16* attnb = (u16*)(ws + 0);               // [4096][4096] bf16 (reuses hbf region)
  u16* wqkvT = (u16*)(ws + 33554432);        // [5120][2880] bf16
  u16* woT   = (u16*)(ws + 63045632);        // [3072][4096] bf16 (rows>=2880 zero)
  u16* q_bf  = (u16*)(ws + 88211456);        // [4096][4096] bf16
  u16* k_bf  = (u16*)(ws + 121765888);       // [4096][512]  bf16
  u16* v_bf  = (u16*)(ws + 125960192);       // [4096][512]  bf16

  f32_to_bf16_k<<<2048, 256, 0, stream>>>(hidden, hbf, 4096 * 2880 / 4);
  transpose_to_bf16_k<<<dim3(2880 / 64, 5120 / 64), 256, 0, stream>>>(w_qkv, wqkvT, 2880, 5120);
  transpose_to_bf16_k<<<dim3(4096 / 64, 3072 / 64), 256, 0, stream>>>(w_o, woT, 4096, 2880);
  // qkv = hidden @ w_qkv + b_qkv, fused YaRN rope + split (M=4096, N=5120, K=2880)
  gemm8p_k<1><<<16 * 20, 512, 0, stream>>>(hbf, wqkvT, nullptr, b_qkv,
                                           2880, 20, 0, 5120, pos, q_bf, k_bf, v_bf);
  attn_k<<<dim3(32, 64), 256, 0, stream>>>(q_bf, k_bf, v_bf, sinks, attnb);
  // out = attn @ w_o + b_o (M=4096, N=2880 pad 3072, K=4096)
  gemm8p_k<0><<<16 * 12, 512, 0, stream>>>(attnb, woT, out, b_o,
                                           4096, 12, 2880, 2880, nullptr, nullptr, nullptr, nullptr);

  (void)in_sizes; (void)n_in; (void)out_size; (void)ws_size;
}